// Round 12
// baseline (512.201 us; speedup 1.0000x reference)
//
#include <hip/hip_runtime.h>
#include <stdint.h>

// CtxAttention: additive attention (Bahdanau).
//   e[n,t]  = sum_a w_v[a] * tanh( enc_pad[n,t,:]·W_enc[a,:] + b_enc[a] + dec_prev[n,:]·W_dec[a,:] )
//   ali     = softmax_t(mask(e));  ctx[n,:] = sum_t ali[n,t] * enc_pad[n,t,:]
// Round-12: standalone enc-convert abandoned for good (6 variants, all ~90 us).
// k_score256: BM=256 x BN=512 (enc read ONCE, full e rows), 1024 threads = 16 waves
// (4M x 4N) -> 4 waves/SIMD (R9/R10 ran 2/SIMD and lost ~2x to pipe serialization).
// A reg-staged fp32 -> cvt f16 once -> ds_write into 80B-stride LDS (2-way banks only);
// B from k-major f16 panels (W16, 512 KB, L2-resident) via GLD16 (proven conflict-free).

#define NB  32
#define TI  2000
#define ED  512
#define AD  512
#define M_TOT (NB * TI)          // 64000
#define NSPLIT 20
#define TCHUNK (TI / NSPLIT)     // 100
#define MTS 250                  // 256-row m-tiles
#define NKS 16                   // K-steps of 32
#define AROWB 80                 // A LDS row stride in bytes (bank-spread)

using f16x8 = __attribute__((ext_vector_type(8))) _Float16;
using f32x4 = __attribute__((ext_vector_type(4))) float;

#define GLD16(g, l)                                                     \
    __builtin_amdgcn_global_load_lds(                                   \
        (const __attribute__((address_space(1))) void*)(g),             \
        (__attribute__((address_space(3))) void*)(l), 16, 0, 0)

__device__ __forceinline__ float fast_tanh(float s) {
    s = fminf(fmaxf(s, -15.f), 15.f);
    float t = __expf(2.f * s);
    return __fdividef(t - 1.f, t + 1.f);
}

__device__ __forceinline__ f16x8 cvt8(float4 a, float4 b) {
    f16x8 h;
    h[0] = (_Float16)a.x; h[1] = (_Float16)a.y; h[2] = (_Float16)a.z; h[3] = (_Float16)a.w;
    h[4] = (_Float16)b.x; h[5] = (_Float16)b.y; h[6] = (_Float16)b.z; h[7] = (_Float16)b.w;
    return h;
}

// ---------------- Kernel 0: W_enc -> W16 (512 KB, k-major panels); + fused decdb ----------
// W16: 16 slabs (ks) of 32 KB; slab = 4 panels (gk) of 8 KB; panel: a (0..511) x 16 B
// holding f16 W_enc[a][ks*32+gk*8 .. +8].
// bx in [0,128): convert; [128,160): decdb row n = bx-128.
__global__ void k_wconvert(const float* __restrict__ Wenc, _Float16* __restrict__ W16,
                           const float* __restrict__ dec_prev, const float* __restrict__ W_dec,
                           const float* __restrict__ b_enc, float* __restrict__ db) {
    __shared__ float xd[ED];
    int bx = blockIdx.x;
    int tid = threadIdx.x;
    if (bx >= 128) {
        int n = bx - 128;
        for (int k = tid; k < ED; k += 256) xd[k] = dec_prev[n * ED + k];
        __syncthreads();
        for (int a = tid; a < AD; a += 256) {
            const float* wr = W_dec + (size_t)a * ED;
            float s = 0.f;
#pragma unroll 8
            for (int k = 0; k < ED; k += 4) {
                float4 w = *(const float4*)(wr + k);
                s += xd[k] * w.x + xd[k + 1] * w.y + xd[k + 2] * w.z + xd[k + 3] * w.w;
            }
            db[n * AD + a] = s + b_enc[a];
        }
        return;
    }
    int idx = bx * 4096 + tid * 16;    // physical byte in W16 (512 KB)
    int ks  = idx >> 15;               // slab 0..15
    int r   = idx & 32767;
    int gk  = r >> 13;                 // panel 0..3
    int a   = (r & 8191) >> 4;         // row 0..511
    int k   = ks * 32 + gk * 8;
    const float* s = Wenc + (size_t)a * ED + k;
    float4 x0 = *(const float4*)s;
    float4 x1 = *(const float4*)(s + 4);
    *(f16x8*)((char*)W16 + idx) = cvt8(x0, x1);
}

// ---------------- standalone decdb (fallback path only) ----------------
__global__ void k_decdb(const float* __restrict__ dec_prev,
                        const float* __restrict__ W_dec,
                        const float* __restrict__ b_enc,
                        float* __restrict__ db) {
    int n = blockIdx.x;
    __shared__ float xd[ED];
    for (int k = threadIdx.x; k < ED; k += 256) xd[k] = dec_prev[n * ED + k];
    __syncthreads();
    for (int a = threadIdx.x; a < AD; a += 256) {
        const float* wr = W_dec + (size_t)a * ED;
        float s = 0.f;
#pragma unroll 8
        for (int k = 0; k < ED; k += 4) {
            float4 w = *(const float4*)(wr + k);
            s += xd[k] * w.x + xd[k + 1] * w.y + xd[k + 2] * w.z + xd[k + 3] * w.w;
        }
        db[n * AD + a] = s + b_enc[a];
    }
}

// ---------------- Kernel 2: fused score GEMM, 256x512 tile, 16 waves, dbuf BK=32 ----------
__launch_bounds__(1024, 1)
__global__ void k_score256(const float* __restrict__ enc, const _Float16* __restrict__ W16,
                           const float* __restrict__ db, const float* __restrict__ wv,
                           float* __restrict__ e_out) {
    __shared__ alignas(16) char As0[256 * AROWB];   // 20 KB: 256 rows x 32 f16, 80B stride
    __shared__ alignas(16) char As1[256 * AROWB];
    __shared__ alignas(16) char Bs0[32768];         // 4 k-panels x (512 x 16B f16)
    __shared__ alignas(16) char Bs1[32768];

    const int mt   = blockIdx.x;
    const int tid  = threadIdx.x;
    const int lane = tid & 63;
    const int w    = tid >> 6;        // wave 0..15
    const int wm   = w >> 2;          // M-quarter: rows wm*64..+64
    const int wn   = w & 3;           // N-quarter: cols wn*128..+128
    const int m0   = mt * 256;
    const int lr   = lane & 15;
    const int gk   = lane >> 4;       // k-group 0..3

    // A staging: thread owns (row = tid>>2, slot = tid&3): 8 floats -> 8 halves.
    const int arow  = tid >> 2;        // 0..255
    const int aslot = tid & 3;         // 16B slot within 64B row
    const float* asrc = enc + (size_t)(m0 + arow) * ED + aslot * 8;
    const int aoff  = arow * AROWB + aslot * 16;

    const char* wbase = (const char*)W16;

    f32x4 acc[4][8];
#pragma unroll
    for (int rb = 0; rb < 4; ++rb)
#pragma unroll
        for (int cb = 0; cb < 8; ++cb) acc[rb][cb] = (f32x4){0.f, 0.f, 0.f, 0.f};

#define STAGE_B(ks, dB)                                                 \
    {                                                                   \
        const char* wsl = wbase + ((ks) << 15);                         \
        GLD16(wsl + tid * 16,          (dB) + tid * 16);                \
        GLD16(wsl + 16384 + tid * 16,  (dB) + 16384 + tid * 16);        \
    }

#define COMPUTE(sA, sB)                                                          \
    {                                                                            \
        f16x8 aF[4], bF[8];                                                      \
        _Pragma("unroll")                                                        \
        for (int rb = 0; rb < 4; ++rb) {                                         \
            int row = wm * 64 + rb * 16 + lr;                                    \
            aF[rb] = *(const f16x8*)((sA) + row * AROWB + gk * 16);              \
        }                                                                        \
        _Pragma("unroll")                                                        \
        for (int cb = 0; cb < 8; ++cb) {                                         \
            int brow = wn * 128 + cb * 16 + lr;                                  \
            bF[cb] = *(const f16x8*)((sB) + gk * 8192 + brow * 16);              \
        }                                                                        \
        __builtin_amdgcn_s_setprio(1);                                           \
        _Pragma("unroll")                                                        \
        for (int rb = 0; rb < 4; ++rb)                                           \
            _Pragma("unroll")                                                    \
            for (int cb = 0; cb < 8; ++cb)                                       \
                acc[rb][cb] = __builtin_amdgcn_mfma_f32_16x16x32_f16(            \
                    aF[rb], bF[cb], acc[rb][cb], 0, 0, 0);                       \
        __builtin_amdgcn_s_setprio(0);                                           \
    }

    // ITER k: issue A-loads(k+1) + B GLD16(k+1) -> COMPUTE(k) hides the latency ->
    // cvt + ds_write A(k+1) (buffer last read in COMPUTE(k-1), safe post-sync) -> sync.
#define ITER(k, Acur, Bcur, Anxt, Bnxt)                                 \
    {                                                                   \
        const float* ap_ = asrc + (k + 1) * 32;                         \
        float4 va_ = *(const float4*)ap_;                               \
        float4 vb_ = *(const float4*)(ap_ + 4);                         \
        STAGE_B(k + 1, Bnxt);                                           \
        __builtin_amdgcn_sched_barrier(0);                              \
        COMPUTE(Acur, Bcur);                                            \
        __builtin_amdgcn_sched_barrier(0);                              \
        *(f16x8*)((Anxt) + aoff) = cvt8(va_, vb_);                      \
        __syncthreads();                                                \
    }

    // prologue: tile 0
    {
        float4 va_ = *(const float4*)asrc;
        float4 vb_ = *(const float4*)(asrc + 4);
        STAGE_B(0, Bs0);
        *(f16x8*)(As0 + aoff) = cvt8(va_, vb_);
        __syncthreads();
    }
    ITER(0,  As0, Bs0, As1, Bs1)
    ITER(1,  As1, Bs1, As0, Bs0)
    ITER(2,  As0, Bs0, As1, Bs1)
    ITER(3,  As1, Bs1, As0, Bs0)
    ITER(4,  As0, Bs0, As1, Bs1)
    ITER(5,  As1, Bs1, As0, Bs0)
    ITER(6,  As0, Bs0, As1, Bs1)
    ITER(7,  As1, Bs1, As0, Bs0)
    ITER(8,  As0, Bs0, As1, Bs1)
    ITER(9,  As1, Bs1, As0, Bs0)
    ITER(10, As0, Bs0, As1, Bs1)
    ITER(11, As1, Bs1, As0, Bs0)
    ITER(12, As0, Bs0, As1, Bs1)
    ITER(13, As1, Bs1, As0, Bs0)
    ITER(14, As0, Bs0, As1, Bs1)
    COMPUTE(As1, Bs1);
    __syncthreads();
#undef ITER
#undef COMPUTE
#undef STAGE_B

    // epilogue: rs = sum over this wave's 128 cols of w_v*tanh(acc+db); shfl-reduce the
    // 16 col-lanes; cross-wave (4 wn quarters) reduce via e_red overlaid on As0.
    float* e_red = (float*)As0;   // [4][256]
    float wvv[8];
#pragma unroll
    for (int cb = 0; cb < 8; ++cb) wvv[cb] = wv[wn * 128 + cb * 16 + lr];

#pragma unroll
    for (int rb = 0; rb < 4; ++rb) {
#pragma unroll
        for (int i = 0; i < 4; ++i) {
            int row_local = wm * 64 + rb * 16 + gk * 4 + i;   // C/D: row=(lane>>4)*4+reg
            int m = m0 + row_local;
            int n = m / TI;
            const float* dbp = db + (size_t)n * AD + wn * 128;
            float rs = 0.f;
#pragma unroll
            for (int cb = 0; cb < 8; ++cb) {
                float s = acc[rb][cb][i] + dbp[cb * 16 + lr];  // col = lane&15
                rs += fast_tanh(s) * wvv[cb];
            }
            rs += __shfl_xor(rs, 1);
            rs += __shfl_xor(rs, 2);
            rs += __shfl_xor(rs, 4);
            rs += __shfl_xor(rs, 8);
            if (lr == 0) e_red[wn * 256 + row_local] = rs;
        }
    }
    __syncthreads();
    if (tid < 256)
        e_out[m0 + tid] =
            e_red[tid] + e_red[256 + tid] + e_red[512 + tid] + e_red[768 + tid];
}

// ---------------- fallback fp32 GEMM (convert-in-kernel) if ws too small ----------------
__launch_bounds__(256, 2)
__global__ void k_score_fb(const float* __restrict__ X, const float* __restrict__ W,
                           const float* __restrict__ db, const float* __restrict__ wv,
                           float* __restrict__ e_part) {
    __shared__ alignas(16) _Float16 Xs[128][72];
    __shared__ alignas(16) _Float16 Ws[128][72];
    __shared__ float e_red[2][128];

    const int tid = threadIdx.x, lane = tid & 63, wid = tid >> 6;
    const int wr = wid >> 1, wc = wid & 1;
    const int m0 = blockIdx.x * 128, a0 = blockIdx.y * 128;

    f32x4 acc[4][4];
#pragma unroll
    for (int rb = 0; rb < 4; ++rb)
#pragma unroll
        for (int cb = 0; cb < 4; ++cb) acc[rb][cb] = (f32x4){0.f, 0.f, 0.f, 0.f};

    const int lr = lane & 15;
    const int lk = (lane >> 4) << 3;

    for (int kt = 0; kt < ED; kt += 64) {
#pragma unroll
        for (int i = 0; i < 4; ++i) {
            int idx = tid + i * 256, r = idx >> 3, c = (idx & 7) << 3;
            const float* gx = X + (size_t)(m0 + r) * ED + kt + c;
            float4 x0 = *(const float4*)gx, x1 = *(const float4*)(gx + 4);
            *(f16x8*)&Xs[r][c] = cvt8(x0, x1);
            const float* gw = W + (size_t)(a0 + r) * ED + kt + c;
            float4 w0 = *(const float4*)gw, w1 = *(const float4*)(gw + 4);
            *(f16x8*)&Ws[r][c] = cvt8(w0, w1);
        }
        __syncthreads();
#pragma unroll
        for (int kb = 0; kb < 64; kb += 32) {
            f16x8 aF[4], bF[4];
#pragma unroll
            for (int rb = 0; rb < 4; ++rb) aF[rb] = *(const f16x8*)&Xs[wr * 64 + rb * 16 + lr][kb + lk];
#pragma unroll
            for (int cb = 0; cb < 4; ++cb) bF[cb] = *(const f16x8*)&Ws[wc * 64 + cb * 16 + lr][kb + lk];
#pragma unroll
            for (int rb = 0; rb < 4; ++rb)
#pragma unroll
                for (int cb = 0; cb < 4; ++cb)
                    acc[rb][cb] = __builtin_amdgcn_mfma_f32_16x16x32_f16(aF[rb], bF[cb], acc[rb][cb], 0, 0, 0);
        }
        __syncthreads();
    }

    const int lg = lane >> 4;
    float wvv[4];
#pragma unroll
    for (int cb = 0; cb < 4; ++cb) wvv[cb] = wv[a0 + wc * 64 + cb * 16 + lr];
#pragma unroll
    for (int rb = 0; rb < 4; ++rb) {
#pragma unroll
        for (int i = 0; i < 4; ++i) {
            int row_local = wr * 64 + rb * 16 + lg * 4 + i;
            int m = m0 + row_local;
            int n = m / TI;
            const float* dbp = db + (size_t)n * AD + a0 + wc * 64;
            float rs = 0.f;
#pragma unroll
            for (int cb = 0; cb < 4; ++cb) {
                float s = acc[rb][cb][i] + dbp[cb * 16 + lr];
                rs += fast_tanh(s) * wvv[cb];
            }
            rs += __shfl_xor(rs, 1);
            rs += __shfl_xor(rs, 2);
            rs += __shfl_xor(rs, 4);
            rs += __shfl_xor(rs, 8);
            if (lr == 0) e_red[wc][row_local] = rs;
        }
    }
    __syncthreads();
    if (tid < 128)
        e_part[(size_t)blockIdx.y * M_TOT + m0 + tid] = e_red[0][tid] + e_red[1][tid];
}

// ---------------- Kernel 3: masked softmax over t, per n ----------------
__global__ void k_softmax(const float* __restrict__ e_part,
                          const int* __restrict__ enc_len,
                          float* __restrict__ ali, int nparts) {
    int n = blockIdx.x;
    int len = enc_len[n];
    __shared__ float se[TI];
    __shared__ float redm[4];
    __shared__ float reds[4];
    int tid = threadIdx.x;
    int lane = tid & 63, wid = tid >> 6;

    for (int t = tid; t < TI; t += 256) {
        float s = 0.f;
        for (int p = 0; p < nparts; ++p) s += e_part[(size_t)p * M_TOT + n * TI + t];
        se[t] = s;
    }
    __syncthreads();

    float mx = -1e30f;
    for (int t = tid; t < len; t += 256) mx = fmaxf(mx, se[t]);
#pragma unroll
    for (int o = 32; o >= 1; o >>= 1) mx = fmaxf(mx, __shfl_xor(mx, o));
    if (lane == 0) redm[wid] = mx;
    __syncthreads();
    mx = fmaxf(fmaxf(redm[0], redm[1]), fmaxf(redm[2], redm[3]));

    float sm = 0.f;
    for (int t = tid; t < len; t += 256) {
        float ex = __expf(se[t] - mx);
        se[t] = ex;
        sm += ex;
    }
#pragma unroll
    for (int o = 32; o >= 1; o >>= 1) sm += __shfl_xor(sm, o);
    if (lane == 0) reds[wid] = sm;
    __syncthreads();
    float inv = 1.f / (reds[0] + reds[1] + reds[2] + reds[3]);

    for (int t = tid; t < TI; t += 256)
        ali[n * TI + t] = (t < len) ? se[t] * inv : 0.f;
}

// ---------------- Kernel 4: ctx partials over t-chunks (fp32 enc, L3-warm) ----------------
__global__ void k_ctxpart(const float* __restrict__ enc,
                          const float* __restrict__ ali,
                          float* __restrict__ cpart) {
    int s = blockIdx.x;   // 0..NSPLIT-1
    int n = blockIdx.y;   // 0..31
    int d0 = threadIdx.x * 2;
    const float* base = enc + ((size_t)n * TI + s * TCHUNK) * ED + d0;
    const float* ap = ali + n * TI + s * TCHUNK;
    float ax = 0.f, ay = 0.f;
#pragma unroll 4
    for (int t = 0; t < TCHUNK; ++t) {
        float a = ap[t];
        float2 v = *(const float2*)(base + (size_t)t * ED);
        ax = fmaf(a, v.x, ax);
        ay = fmaf(a, v.y, ay);
    }
    float2 r; r.x = ax; r.y = ay;
    *(float2*)&cpart[((size_t)(n * NSPLIT + s)) * ED + d0] = r;
}

// ---------------- Kernel 5: reduce ctx partials ----------------
__global__ void k_ctxred(const float* __restrict__ cpart, float* __restrict__ ctx) {
    int n = blockIdx.x;
    for (int d = threadIdx.x; d < ED; d += 256) {
        float sum = 0.f;
#pragma unroll
        for (int s = 0; s < NSPLIT; ++s) sum += cpart[((size_t)(n * NSPLIT + s)) * ED + d];
        ctx[(size_t)n * ED + d] = sum;
    }
}

extern "C" void kernel_launch(void* const* d_in, const int* in_sizes, int n_in,
                              void* d_out, int out_size, void* d_ws, size_t ws_size,
                              hipStream_t stream) {
    const float* enc_pad  = (const float*)d_in[0];
    const int*   enc_len  = (const int*)d_in[1];
    const float* dec_prev = (const float*)d_in[2];
    // d_in[3] = ali_prev (unused by reference)
    const float* W_enc    = (const float*)d_in[4];
    const float* b_enc    = (const float*)d_in[5];
    const float* W_dec    = (const float*)d_in[6];
    const float* w_v      = (const float*)d_in[7];

    float* out = (float*)d_out;
    float* ali = out;              // 64000 floats
    float* ctx = out + M_TOT;      // 16384 floats

    float* ws     = (float*)d_ws;
    float* db     = ws;                          // 32*512
    float* e_part = ws + NB * AD;                // up to 4*64000 (main path uses 1)
    float* cpart  = e_part + 4 * M_TOT;          // 32*20*512
    size_t fp_floats = (size_t)NB * AD + 4 * M_TOT + (size_t)NB * NSPLIT * ED;  // 600064
    _Float16* W16 = (_Float16*)((char*)d_ws + fp_floats * 4);
    size_t need = fp_floats * 4 + (size_t)512 * 1024;   // ~2.9 MB
    bool big = ws_size >= need;

    if (big) {
        hipLaunchKernelGGL(k_wconvert, dim3(160), dim3(256), 0, stream,
                           W_enc, W16, dec_prev, W_dec, b_enc, db);
        hipLaunchKernelGGL(k_score256, dim3(MTS), dim3(1024), 0, stream,
                           enc_pad, W16, db, w_v, e_part);
        hipLaunchKernelGGL(k_softmax, dim3(NB), dim3(256), 0, stream, e_part, enc_len, ali, 1);
    } else {
        hipLaunchKernelGGL(k_decdb, dim3(NB), dim3(256), 0, stream, dec_prev, W_dec, b_enc, db);
        hipLaunchKernelGGL(k_score_fb, dim3(M_TOT / 128, 4), dim3(256), 0, stream,
                           enc_pad, W_enc, db, w_v, e_part);
        hipLaunchKernelGGL(k_softmax, dim3(NB), dim3(256), 0, stream, e_part, enc_len, ali, 4);
    }
    hipLaunchKernelGGL(k_ctxpart, dim3(NSPLIT, NB), dim3(256), 0, stream, enc_pad, ali, cpart);
    hipLaunchKernelGGL(k_ctxred, dim3(NB), dim3(256), 0, stream, cpart, ctx);
}

// Round 13
// 122.008 us; speedup vs baseline: 4.1981x; 4.1981x over previous
//
#include <hip/hip_runtime.h>
#include <stdint.h>

// CtxAttention: additive attention (Bahdanau).
//   e[n,t]  = sum_a w_v[a] * tanh( enc_pad[n,t,:]·W_enc[a,:] + b_enc[a] + dec_prev[n,:]·W_dec[a,:] )
//   ali     = softmax_t(mask(e));  ctx[n,:] = sum_t ali[n,t] * enc_pad[n,t,:]
// Round-13: R12's mechanism (4 waves/SIMD) with a LEGAL register budget. 1024 thr =
// 16 waves, per-wave output 64x64 -> acc[4][4] = 64 regs (R12 used 64x128 -> acc 128
// -> forced spill, 1.2 GB scratch, 511 us). BM=128 x BN=512 (enc read once), BK=32
// dbuf; A fp32 GLD16 -> XOR-swizzled LDS (R9-verified, 2-way free) + cvt-on-read;
// B k-major f16 panels via GLD16 (R9-verified conflict-free). LDS 96 KB.

#define NB  32
#define TI  2000
#define ED  512
#define AD  512
#define M_TOT (NB * TI)          // 64000
#define NSPLIT 20
#define TCHUNK (TI / NSPLIT)     // 100
#define MTS 500                  // 128-row m-tiles
#define NKS 16                   // K-steps of 32

using f16x8 = __attribute__((ext_vector_type(8))) _Float16;
using f32x4 = __attribute__((ext_vector_type(4))) float;

#define GLD16(g, l)                                                     \
    __builtin_amdgcn_global_load_lds(                                   \
        (const __attribute__((address_space(1))) void*)(g),             \
        (__attribute__((address_space(3))) void*)(l), 16, 0, 0)

__device__ __forceinline__ float fast_tanh(float s) {
    s = fminf(fmaxf(s, -15.f), 15.f);
    float t = __expf(2.f * s);
    return __fdividef(t - 1.f, t + 1.f);
}

__device__ __forceinline__ f16x8 cvt8(float4 a, float4 b) {
    f16x8 h;
    h[0] = (_Float16)a.x; h[1] = (_Float16)a.y; h[2] = (_Float16)a.z; h[3] = (_Float16)a.w;
    h[4] = (_Float16)b.x; h[5] = (_Float16)b.y; h[6] = (_Float16)b.z; h[7] = (_Float16)b.w;
    return h;
}

// ---------------- Kernel 0: W_enc -> W16 (512 KB, k-major panels); + fused decdb ----------
// W16: 16 slabs (ks) of 32 KB; slab = 4 panels (gk) of 8 KB; panel: a (0..511) x 16 B
// holding f16 W_enc[a][ks*32+gk*8 .. +8].
// bx in [0,128): convert; [128,160): decdb row n = bx-128.
__global__ void k_wconvert(const float* __restrict__ Wenc, _Float16* __restrict__ W16,
                           const float* __restrict__ dec_prev, const float* __restrict__ W_dec,
                           const float* __restrict__ b_enc, float* __restrict__ db) {
    __shared__ float xd[ED];
    int bx = blockIdx.x;
    int tid = threadIdx.x;
    if (bx >= 128) {
        int n = bx - 128;
        for (int k = tid; k < ED; k += 256) xd[k] = dec_prev[n * ED + k];
        __syncthreads();
        for (int a = tid; a < AD; a += 256) {
            const float* wr = W_dec + (size_t)a * ED;
            float s = 0.f;
#pragma unroll 8
            for (int k = 0; k < ED; k += 4) {
                float4 w = *(const float4*)(wr + k);
                s += xd[k] * w.x + xd[k + 1] * w.y + xd[k + 2] * w.z + xd[k + 3] * w.w;
            }
            db[n * AD + a] = s + b_enc[a];
        }
        return;
    }
    int idx = bx * 4096 + tid * 16;    // physical byte in W16 (512 KB)
    int ks  = idx >> 15;               // slab 0..15
    int r   = idx & 32767;
    int gk  = r >> 13;                 // panel 0..3
    int a   = (r & 8191) >> 4;         // row 0..511
    int k   = ks * 32 + gk * 8;
    const float* s = Wenc + (size_t)a * ED + k;
    float4 x0 = *(const float4*)s;
    float4 x1 = *(const float4*)(s + 4);
    *(f16x8*)((char*)W16 + idx) = cvt8(x0, x1);
}

// ---------------- standalone decdb (fallback path only) ----------------
__global__ void k_decdb(const float* __restrict__ dec_prev,
                        const float* __restrict__ W_dec,
                        const float* __restrict__ b_enc,
                        float* __restrict__ db) {
    int n = blockIdx.x;
    __shared__ float xd[ED];
    for (int k = threadIdx.x; k < ED; k += 256) xd[k] = dec_prev[n * ED + k];
    __syncthreads();
    for (int a = threadIdx.x; a < AD; a += 256) {
        const float* wr = W_dec + (size_t)a * ED;
        float s = 0.f;
#pragma unroll 8
        for (int k = 0; k < ED; k += 4) {
            float4 w = *(const float4*)(wr + k);
            s += xd[k] * w.x + xd[k + 1] * w.y + xd[k + 2] * w.z + xd[k + 3] * w.w;
        }
        db[n * AD + a] = s + b_enc[a];
    }
}

// ---------------- Kernel 2: fused score GEMM, 128x512 tile, 16 waves (64x64/wave) ----------
__launch_bounds__(1024, 1)
__global__ void k_score256(const float* __restrict__ enc, const _Float16* __restrict__ W16,
                           const float* __restrict__ db, const float* __restrict__ wv,
                           float* __restrict__ e_out) {
    __shared__ alignas(16) char As0[16384];   // 128 x 32 fp32, 128B rows, XOR-swizzled
    __shared__ alignas(16) char As1[16384];
    __shared__ alignas(16) char Bs0[32768];   // 4 k-panels x (512 x 16B f16), linear
    __shared__ alignas(16) char Bs1[32768];

    const int mt   = blockIdx.x;
    const int tid  = threadIdx.x;
    const int lane = tid & 63;
    const int w    = tid >> 6;        // wave 0..15
    const int wm   = w >> 3;          // M-half: rows wm*64..+64
    const int wn   = w & 7;           // N-eighth: cols wn*64..+64
    const int m0   = mt * 128;
    const int lr   = lane & 15;
    const int gk   = lane >> 4;       // k-group 0..3

    // A staging: 1 GLD16/thread. Linear LDS byte tid*16 = row*(128B) + slot*16;
    // global source pre-swizzled (inverse of the read-side XOR).
    const int arow = tid >> 3;                        // 0..127
    const int sq   = (tid & 7) * 16;                  // byte col in 128B row
    const int sqx  = (sq ^ ((arow & 7) << 4)) >> 2;   // float offset, inverse-swizzled
    const float* asrc = enc + (size_t)(m0 + arow) * ED + sqx;

    const char* wbase = (const char*)W16;

    f32x4 acc[4][4];
#pragma unroll
    for (int rb = 0; rb < 4; ++rb)
#pragma unroll
        for (int cb = 0; cb < 4; ++cb) acc[rb][cb] = (f32x4){0.f, 0.f, 0.f, 0.f};

#define STAGE(ks, dA, dB)                                               \
    {                                                                   \
        GLD16(asrc + (ks) * 32, (dA) + tid * 16);                       \
        const char* wsl = wbase + ((ks) << 15);                         \
        GLD16(wsl + tid * 16,          (dB) + tid * 16);                \
        GLD16(wsl + 16384 + tid * 16,  (dB) + 16384 + tid * 16);        \
    }

#define COMPUTE(sA, sB)                                                          \
    {                                                                            \
        f16x8 aF[4], bF[4];                                                      \
        _Pragma("unroll")                                                        \
        for (int rb = 0; rb < 4; ++rb) {                                         \
            int row = wm * 64 + rb * 16 + lr;                                    \
            int b0  = row * 128 + gk * 32;                                       \
            int sw  = (row & 7) << 4;                                            \
            f32x4 lo = *(const f32x4*)((sA) + (b0 ^ sw));                        \
            f32x4 hi = *(const f32x4*)((sA) + ((b0 + 16) ^ sw));                 \
            f16x8 h;                                                             \
            h[0] = (_Float16)lo[0]; h[1] = (_Float16)lo[1];                      \
            h[2] = (_Float16)lo[2]; h[3] = (_Float16)lo[3];                      \
            h[4] = (_Float16)hi[0]; h[5] = (_Float16)hi[1];                      \
            h[6] = (_Float16)hi[2]; h[7] = (_Float16)hi[3];                      \
            aF[rb] = h;                                                          \
        }                                                                        \
        _Pragma("unroll")                                                        \
        for (int cb = 0; cb < 4; ++cb) {                                         \
            int brow = wn * 64 + cb * 16 + lr;                                   \
            bF[cb] = *(const f16x8*)((sB) + gk * 8192 + brow * 16);              \
        }                                                                        \
        __builtin_amdgcn_s_setprio(1);                                           \
        _Pragma("unroll")                                                        \
        for (int rb = 0; rb < 4; ++rb)                                           \
            _Pragma("unroll")                                                    \
            for (int cb = 0; cb < 4; ++cb)                                       \
                acc[rb][cb] = __builtin_amdgcn_mfma_f32_16x16x32_f16(            \
                    aF[rb], bF[cb], acc[rb][cb], 0, 0, 0);                       \
        __builtin_amdgcn_s_setprio(0);                                           \
    }

#define ITER(k, Ac, Bc, An, Bn)  STAGE(k + 1, An, Bn); COMPUTE(Ac, Bc); __syncthreads();

    STAGE(0, As0, Bs0); __syncthreads();
    ITER(0,  As0, Bs0, As1, Bs1)
    ITER(1,  As1, Bs1, As0, Bs0)
    ITER(2,  As0, Bs0, As1, Bs1)
    ITER(3,  As1, Bs1, As0, Bs0)
    ITER(4,  As0, Bs0, As1, Bs1)
    ITER(5,  As1, Bs1, As0, Bs0)
    ITER(6,  As0, Bs0, As1, Bs1)
    ITER(7,  As1, Bs1, As0, Bs0)
    ITER(8,  As0, Bs0, As1, Bs1)
    ITER(9,  As1, Bs1, As0, Bs0)
    ITER(10, As0, Bs0, As1, Bs1)
    ITER(11, As1, Bs1, As0, Bs0)
    ITER(12, As0, Bs0, As1, Bs1)
    ITER(13, As1, Bs1, As0, Bs0)
    ITER(14, As0, Bs0, As1, Bs1)
    COMPUTE(As1, Bs1); __syncthreads();
#undef ITER
#undef COMPUTE
#undef STAGE

    // epilogue: rs = sum over this wave's 64 cols of w_v*tanh(acc+db); shfl-reduce the
    // 16 col-lanes; cross-wave (8 wn eighths) reduce via e_red overlaid on As0+As1.
    float* e_red = (float*)As0;   // [8][128] = 4 KB (fits As0)
    float wvv[4];
#pragma unroll
    for (int cb = 0; cb < 4; ++cb) wvv[cb] = wv[wn * 64 + cb * 16 + lr];

#pragma unroll
    for (int rb = 0; rb < 4; ++rb) {
#pragma unroll
        for (int i = 0; i < 4; ++i) {
            int row_local = wm * 64 + rb * 16 + gk * 4 + i;   // C/D: row=(lane>>4)*4+reg
            int m = m0 + row_local;
            int n = m / TI;
            const float* dbp = db + (size_t)n * AD + wn * 64;
            float rs = 0.f;
#pragma unroll
            for (int cb = 0; cb < 4; ++cb) {
                float s = acc[rb][cb][i] + dbp[cb * 16 + lr];  // col = lane&15
                rs += fast_tanh(s) * wvv[cb];
            }
            rs += __shfl_xor(rs, 1);
            rs += __shfl_xor(rs, 2);
            rs += __shfl_xor(rs, 4);
            rs += __shfl_xor(rs, 8);
            if (lr == 0) e_red[wn * 128 + row_local] = rs;
        }
    }
    __syncthreads();
    if (tid < 128) {
        float s = 0.f;
#pragma unroll
        for (int q = 0; q < 8; ++q) s += e_red[q * 128 + tid];
        e_out[m0 + tid] = s;
    }
}

// ---------------- fallback fp32 GEMM (convert-in-kernel) if ws too small ----------------
__launch_bounds__(256, 2)
__global__ void k_score_fb(const float* __restrict__ X, const float* __restrict__ W,
                           const float* __restrict__ db, const float* __restrict__ wv,
                           float* __restrict__ e_part) {
    __shared__ alignas(16) _Float16 Xs[128][72];
    __shared__ alignas(16) _Float16 Ws[128][72];
    __shared__ float e_red[2][128];

    const int tid = threadIdx.x, lane = tid & 63, wid = tid >> 6;
    const int wr = wid >> 1, wc = wid & 1;
    const int m0 = blockIdx.x * 128, a0 = blockIdx.y * 128;

    f32x4 acc[4][4];
#pragma unroll
    for (int rb = 0; rb < 4; ++rb)
#pragma unroll
        for (int cb = 0; cb < 4; ++cb) acc[rb][cb] = (f32x4){0.f, 0.f, 0.f, 0.f};

    const int lr = lane & 15;
    const int lk = (lane >> 4) << 3;

    for (int kt = 0; kt < ED; kt += 64) {
#pragma unroll
        for (int i = 0; i < 4; ++i) {
            int idx = tid + i * 256, r = idx >> 3, c = (idx & 7) << 3;
            const float* gx = X + (size_t)(m0 + r) * ED + kt + c;
            float4 x0 = *(const float4*)gx, x1 = *(const float4*)(gx + 4);
            *(f16x8*)&Xs[r][c] = cvt8(x0, x1);
            const float* gw = W + (size_t)(a0 + r) * ED + kt + c;
            float4 w0 = *(const float4*)gw, w1 = *(const float4*)(gw + 4);
            *(f16x8*)&Ws[r][c] = cvt8(w0, w1);
        }
        __syncthreads();
#pragma unroll
        for (int kb = 0; kb < 64; kb += 32) {
            f16x8 aF[4], bF[4];
#pragma unroll
            for (int rb = 0; rb < 4; ++rb) aF[rb] = *(const f16x8*)&Xs[wr * 64 + rb * 16 + lr][kb + lk];
#pragma unroll
            for (int cb = 0; cb < 4; ++cb) bF[cb] = *(const f16x8*)&Ws[wc * 64 + cb * 16 + lr][kb + lk];
#pragma unroll
            for (int rb = 0; rb < 4; ++rb)
#pragma unroll
                for (int cb = 0; cb < 4; ++cb)
                    acc[rb][cb] = __builtin_amdgcn_mfma_f32_16x16x32_f16(aF[rb], bF[cb], acc[rb][cb], 0, 0, 0);
        }
        __syncthreads();
    }

    const int lg = lane >> 4;
    float wvv[4];
#pragma unroll
    for (int cb = 0; cb < 4; ++cb) wvv[cb] = wv[a0 + wc * 64 + cb * 16 + lr];
#pragma unroll
    for (int rb = 0; rb < 4; ++rb) {
#pragma unroll
        for (int i = 0; i < 4; ++i) {
            int row_local = wr * 64 + rb * 16 + lg * 4 + i;
            int m = m0 + row_local;
            int n = m / TI;
            const float* dbp = db + (size_t)n * AD + a0 + wc * 64;
            float rs = 0.f;
#pragma unroll
            for (int cb = 0; cb < 4; ++cb) {
                float s = acc[rb][cb][i] + dbp[cb * 16 + lr];
                rs += fast_tanh(s) * wvv[cb];
            }
            rs += __shfl_xor(rs, 1);
            rs += __shfl_xor(rs, 2);
            rs += __shfl_xor(rs, 4);
            rs += __shfl_xor(rs, 8);
            if (lr == 0) e_red[wc][row_local] = rs;
        }
    }
    __syncthreads();
    if (tid < 128)
        e_part[(size_t)blockIdx.y * M_TOT + m0 + tid] = e_red[0][tid] + e_red[1][tid];
}

// ---------------- Kernel 3: masked softmax over t, per n ----------------
__global__ void k_softmax(const float* __restrict__ e_part,
                          const int* __restrict__ enc_len,
                          float* __restrict__ ali, int nparts) {
    int n = blockIdx.x;
    int len = enc_len[n];
    __shared__ float se[TI];
    __shared__ float redm[4];
    __shared__ float reds[4];
    int tid = threadIdx.x;
    int lane = tid & 63, wid = tid >> 6;

    for (int t = tid; t < TI; t += 256) {
        float s = 0.f;
        for (int p = 0; p < nparts; ++p) s += e_part[(size_t)p * M_TOT + n * TI + t];
        se[t] = s;
    }
    __syncthreads();

    float mx = -1e30f;
    for (int t = tid; t < len; t += 256) mx = fmaxf(mx, se[t]);
#pragma unroll
    for (int o = 32; o >= 1; o >>= 1) mx = fmaxf(mx, __shfl_xor(mx, o));
    if (lane == 0) redm[wid] = mx;
    __syncthreads();
    mx = fmaxf(fmaxf(redm[0], redm[1]), fmaxf(redm[2], redm[3]));

    float sm = 0.f;
    for (int t = tid; t < len; t += 256) {
        float ex = __expf(se[t] - mx);
        se[t] = ex;
        sm += ex;
    }
#pragma unroll
    for (int o = 32; o >= 1; o >>= 1) sm += __shfl_xor(sm, o);
    if (lane == 0) reds[wid] = sm;
    __syncthreads();
    float inv = 1.f / (reds[0] + reds[1] + reds[2] + reds[3]);

    for (int t = tid; t < TI; t += 256)
        ali[n * TI + t] = (t < len) ? se[t] * inv : 0.f;
}

// ---------------- Kernel 4: ctx partials over t-chunks (fp32 enc, L3-warm) ----------------
__global__ void k_ctxpart(const float* __restrict__ enc,
                          const float* __restrict__ ali,
                          float* __restrict__ cpart) {
    int s = blockIdx.x;   // 0..NSPLIT-1
    int n = blockIdx.y;   // 0..31
    int d0 = threadIdx.x * 2;
    const float* base = enc + ((size_t)n * TI + s * TCHUNK) * ED + d0;
    const float* ap = ali + n * TI + s * TCHUNK;
    float ax = 0.f, ay = 0.f;
#pragma unroll 4
    for (int t = 0; t < TCHUNK; ++t) {
        float a = ap[t];
        float2 v = *(const float2*)(base + (size_t)t * ED);
        ax = fmaf(a, v.x, ax);
        ay = fmaf(a, v.y, ay);
    }
    float2 r; r.x = ax; r.y = ay;
    *(float2*)&cpart[((size_t)(n * NSPLIT + s)) * ED + d0] = r;
}

// ---------------- Kernel 5: reduce ctx partials ----------------
__global__ void k_ctxred(const float* __restrict__ cpart, float* __restrict__ ctx) {
    int n = blockIdx.x;
    for (int d = threadIdx.x; d < ED; d += 256) {
        float sum = 0.f;
#pragma unroll
        for (int s = 0; s < NSPLIT; ++s) sum += cpart[((size_t)(n * NSPLIT + s)) * ED + d];
        ctx[(size_t)n * ED + d] = sum;
    }
}

extern "C" void kernel_launch(void* const* d_in, const int* in_sizes, int n_in,
                              void* d_out, int out_size, void* d_ws, size_t ws_size,
                              hipStream_t stream) {
    const float* enc_pad  = (const float*)d_in[0];
    const int*   enc_len  = (const int*)d_in[1];
    const float* dec_prev = (const float*)d_in[2];
    // d_in[3] = ali_prev (unused by reference)
    const float* W_enc    = (const float*)d_in[4];
    const float* b_enc    = (const float*)d_in[5];
    const float* W_dec    = (const float*)d_in[6];
    const float* w_v      = (const float*)d_in[7];

    float* out = (float*)d_out;
    float* ali = out;              // 64000 floats
    float* ctx = out + M_TOT;      // 16384 floats

    float* ws     = (float*)d_ws;
    float* db     = ws;                          // 32*512
    float* e_part = ws + NB * AD;                // up to 4*64000 (main path uses 1)
    float* cpart  = e_part + 4 * M_TOT;          // 32*20*512
    size_t fp_floats = (size_t)NB * AD + 4 * M_TOT + (size_t)NB * NSPLIT * ED;  // 600064
    _Float16* W16 = (_Float16*)((char*)d_ws + fp_floats * 4);
    size_t need = fp_floats * 4 + (size_t)512 * 1024;   // ~2.9 MB
    bool big = ws_size >= need;

    if (big) {
        hipLaunchKernelGGL(k_wconvert, dim3(160), dim3(256), 0, stream,
                           W_enc, W16, dec_prev, W_dec, b_enc, db);
        hipLaunchKernelGGL(k_score256, dim3(MTS), dim3(1024), 0, stream,
                           enc_pad, W16, db, w_v, e_part);
        hipLaunchKernelGGL(k_softmax, dim3(NB), dim3(256), 0, stream, e_part, enc_len, ali, 1);
    } else {
        hipLaunchKernelGGL(k_decdb, dim3(NB), dim3(256), 0, stream, dec_prev, W_dec, b_enc, db);
        hipLaunchKernelGGL(k_score_fb, dim3(M_TOT / 128, 4), dim3(256), 0, stream,
                           enc_pad, W_enc, db, w_v, e_part);
        hipLaunchKernelGGL(k_softmax, dim3(NB), dim3(256), 0, stream, e_part, enc_len, ali, 4);
    }
    hipLaunchKernelGGL(k_ctxpart, dim3(NSPLIT, NB), dim3(256), 0, stream, enc_pad, ali, cpart);
    hipLaunchKernelGGL(k_ctxred, dim3(NB), dim3(256), 0, stream, cpart, ctx);
}